// Round 1
// baseline (633.769 us; speedup 1.0000x reference)
//
#include <hip/hip_runtime.h>
#include <hip/hip_bf16.h>
#include <stdint.h>

// CoAttention: B=64, C=1024, H=W=16 (N=256), CK=128.
// out_x = gamma1 * (vx @ softmax(kx^T ky)^T) + x ; out_y symmetric with E^T.
#define B_  64
#define C_  1024
#define CK_ 128
#define N_  256

typedef __bf16 bf16;
typedef __attribute__((ext_vector_type(8))) __bf16 bf16x8;
typedef __attribute__((ext_vector_type(4))) __bf16 bf16x4;
typedef __attribute__((ext_vector_type(4))) float floatx4;

// ---- workspace layout (bytes) ----
constexpr size_t OFF_XBT = 0;                 // bf16 [64][256][1024]  x transposed
constexpr size_t OFF_YBT = 33554432;          // bf16 [64][256][1024]
constexpr size_t OFF_WK1 = 67108864;          // bf16 [128][1024]
constexpr size_t OFF_WK2 = 67371008;
constexpr size_t OFF_WV1 = 67633152;          // bf16 [1024][1024]
constexpr size_t OFF_WV2 = 69730304;
constexpr size_t OFF_KXT = 71827456;          // bf16 [64][256][128]  (kx transposed)
constexpr size_t OFF_KYT = 76021760;
constexpr size_t OFF_AX  = 71827456;          // bf16 [64][256][256]  aliases kxT/kyT (dead after energy)
constexpr size_t OFF_AY  = 80216064;
constexpr size_t WS_NEEDED = 88604672;

__device__ __forceinline__ void async16(const void* g, void* l) {
  // global -> LDS direct, 16B/lane; LDS dest is wave-uniform base + lane*16
  __builtin_amdgcn_global_load_lds((const __attribute__((address_space(1))) void*)g,
                                   (__attribute__((address_space(3))) void*)l, 16, 0, 0);
}

// fp32 [C][N] -> bf16 [N][C] transpose (per 64x64 tile via LDS)
__global__ __launch_bounds__(256) void k_xpose(const float* __restrict__ in,
                                               bf16* __restrict__ out) {
  __shared__ float tile[64][65];
  int nt = blockIdx.x, ct = blockIdx.y, b = blockIdx.z;
  const float* src = in + (size_t)b * C_ * N_ + (size_t)ct * 64 * N_ + nt * 64;
  bf16* dst = out + (size_t)b * N_ * C_ + (size_t)nt * 64 * C_ + ct * 64;
  int col = threadIdx.x & 63, r0 = threadIdx.x >> 6;
#pragma unroll
  for (int i = 0; i < 16; ++i) {
    int r = r0 + i * 4;
    tile[r][col] = src[r * N_ + col];     // coalesced along n
  }
  __syncthreads();
#pragma unroll
  for (int i = 0; i < 16; ++i) {
    int r = r0 + i * 4;                   // n-local
    dst[r * C_ + col] = (bf16)tile[col][r]; // coalesced along c, stride-65 LDS: conflict-free
  }
}

// fp32 -> bf16 elementwise (n4 = elems/4)
__global__ __launch_bounds__(256) void k_cvt(const float* __restrict__ in,
                                             bf16* __restrict__ out, int n4) {
  int i = blockIdx.x * 256 + threadIdx.x;
  if (i < n4) {
    float4 v = ((const float4*)in)[i];
    bf16x4 o;
    o[0] = (bf16)v.x; o[1] = (bf16)v.y; o[2] = (bf16)v.z; o[3] = (bf16)v.w;
    ((bf16x4*)out)[i] = o;
  }
}

// Shared 128x128 GEMM core: A[m][k] (ldA), BT[n][k] (ldB), K = KITERS*32.
// 4 waves 2x2, each 64x64 via 4x4 mfma_f32_16x16x32_bf16 tiles.
// LDS: As[128][32] @0 (8KB, chunk-XOR swizzled), Bs[128][32] @8192.
template <int KITERS>
__device__ __forceinline__ void gemm128_core(const bf16* __restrict__ Ag, int ldA,
                                             const bf16* __restrict__ Bg, int ldB,
                                             char* smem, floatx4 (&acc)[4][4]) {
  const int tid = threadIdx.x;
  const int l = tid & 63, wid = tid >> 6;
  const int wm = wid & 1, wn = wid >> 1;
  for (int kt = 0; kt < KITERS; ++kt) {
    const int k0 = kt * 32;
#pragma unroll
    for (int s = 0; s < 2; ++s) {
      int row = (s << 6) + (wid << 4) + (l >> 2);        // LDS-local row 0..127
      int q = (l & 3) ^ ((row >> 1) & 3);                // swizzled source chunk
      async16(Ag + (size_t)row * ldA + k0 + q * 8, smem + (s << 12) + (wid << 10));
      async16(Bg + (size_t)row * ldB + k0 + q * 8, smem + 8192 + (s << 12) + (wid << 10));
    }
    __syncthreads();   // drains vmcnt before consuming LDS
    bf16x8 af[4], bfr[4];
#pragma unroll
    for (int t = 0; t < 4; ++t) {
      int m = (wm << 6) + t * 16 + (l & 15);
      af[t] = *(const bf16x8*)(smem + m * 64 + ((((l >> 4) ^ ((m >> 1) & 3)) << 4)));
      int n = (wn << 6) + t * 16 + (l & 15);
      bfr[t] = *(const bf16x8*)(smem + 8192 + n * 64 + ((((l >> 4) ^ ((n >> 1) & 3)) << 4)));
    }
#pragma unroll
    for (int tm = 0; tm < 4; ++tm)
#pragma unroll
      for (int tn = 0; tn < 4; ++tn)
        acc[tm][tn] = __builtin_amdgcn_mfma_f32_16x16x32_bf16(af[tm], bfr[tn], acc[tm][tn], 0, 0, 0);
    __syncthreads();
  }
}

// kT[n][o] = sum_c xbT[n][c]*wk[o][c] + bk[o]  (M=256 -> 2 tiles, N=128, K=1024)
__global__ __launch_bounds__(256) void k_projk(
    const bf16* __restrict__ xbT, const bf16* __restrict__ ybT,
    const bf16* __restrict__ wk1b, const bf16* __restrict__ wk2b,
    const float* __restrict__ bk1, const float* __restrict__ bk2,
    bf16* __restrict__ kxT, bf16* __restrict__ kyT) {
  __shared__ __align__(16) char smem[16384];
  int mt = blockIdx.x, br = blockIdx.y, b = blockIdx.z;
  const bf16* A = (br ? ybT : xbT) + (size_t)b * N_ * C_ + (size_t)mt * 128 * C_;
  const bf16* Bt = br ? wk2b : wk1b;
  const float* bias = br ? bk2 : bk1;
  bf16* out = (br ? kyT : kxT) + (size_t)b * N_ * CK_ + (size_t)mt * 128 * CK_;
  floatx4 acc[4][4];
  floatx4 z = {0.f, 0.f, 0.f, 0.f};
#pragma unroll
  for (int i = 0; i < 4; ++i)
#pragma unroll
    for (int j = 0; j < 4; ++j) acc[i][j] = z;
  gemm128_core<32>(A, C_, Bt, C_, smem, acc);
  const int l = threadIdx.x & 63, wid = threadIdx.x >> 6;
  const int wm = wid & 1, wn = wid >> 1;
#pragma unroll
  for (int tn = 0; tn < 4; ++tn) {
    int oc = (wn << 6) + tn * 16 + (l & 15);
    float bkv = bias[oc];
#pragma unroll
    for (int tm = 0; tm < 4; ++tm)
#pragma unroll
      for (int r = 0; r < 4; ++r) {
        int row = (wm << 6) + tm * 16 + ((l >> 4) << 2) + r;
        out[row * CK_ + oc] = (bf16)(acc[tm][tn][r] + bkv);
      }
  }
}

// E[m][n] = sum_o kxT[m][o]*kyT[n][o]  fp32 (K=128)
__global__ __launch_bounds__(256) void k_energy(const bf16* __restrict__ kxT,
                                                const bf16* __restrict__ kyT,
                                                float* __restrict__ E) {
  __shared__ __align__(16) char smem[16384];
  int mt = blockIdx.x, nt = blockIdx.y, b = blockIdx.z;
  const bf16* A = kxT + (size_t)b * N_ * CK_ + (size_t)mt * 128 * CK_;
  const bf16* Bt = kyT + (size_t)b * N_ * CK_ + (size_t)nt * 128 * CK_;
  float* out = E + (size_t)b * N_ * N_ + (size_t)mt * 128 * N_ + nt * 128;
  floatx4 acc[4][4];
  floatx4 z = {0.f, 0.f, 0.f, 0.f};
#pragma unroll
  for (int i = 0; i < 4; ++i)
#pragma unroll
    for (int j = 0; j < 4; ++j) acc[i][j] = z;
  gemm128_core<4>(A, CK_, Bt, CK_, smem, acc);
  const int l = threadIdx.x & 63, wid = threadIdx.x >> 6;
  const int wm = wid & 1, wn = wid >> 1;
#pragma unroll
  for (int tm = 0; tm < 4; ++tm)
#pragma unroll
    for (int tn = 0; tn < 4; ++tn)
#pragma unroll
      for (int r = 0; r < 4; ++r) {
        int row = (wm << 6) + tm * 16 + ((l >> 4) << 2) + r;
        int col = (wn << 6) + tn * 16 + (l & 15);
        out[row * N_ + col] = acc[tm][tn][r];
      }
}

// attn_x[m][n] = softmax over n of E[m][n]; attn_y[m][n] = softmax over n of E[n][m]
__global__ __launch_bounds__(256) void k_softmax(const float* __restrict__ E,
                                                 bf16* __restrict__ ax,
                                                 bf16* __restrict__ ay) {
  __shared__ float rmaxS[256], rrcpS[256];
  int b = blockIdx.x;
  const float* e = E + (size_t)b * N_ * N_;
  int tid = threadIdx.x, l = tid & 63, wid = tid >> 6;
  // column stats (thread tid owns column tid) -- coalesced
  float cm = -1e30f;
  for (int i = 0; i < 256; ++i) cm = fmaxf(cm, e[i * 256 + tid]);
  float cs = 0.f;
  for (int i = 0; i < 256; ++i) cs += __expf(e[i * 256 + tid] - cm);
  float crcp = 1.0f / cs;
  // row stats: wave per row, shuffle reduce
  for (int m = wid; m < 256; m += 4) {
    const float* row = e + m * 256;
    float v0 = row[l], v1 = row[l + 64], v2 = row[l + 128], v3 = row[l + 192];
    float mx = fmaxf(fmaxf(v0, v1), fmaxf(v2, v3));
#pragma unroll
    for (int off = 32; off > 0; off >>= 1) mx = fmaxf(mx, __shfl_xor(mx, off));
    float s = __expf(v0 - mx) + __expf(v1 - mx) + __expf(v2 - mx) + __expf(v3 - mx);
#pragma unroll
    for (int off = 32; off > 0; off >>= 1) s += __shfl_xor(s, off);
    if (l == 0) { rmaxS[m] = mx; rrcpS[m] = 1.0f / s; }
  }
  __syncthreads();
  bf16* axb = ax + (size_t)b * N_ * N_;
  bf16* ayb = ay + (size_t)b * N_ * N_;
  for (int m = 0; m < 256; ++m) {
    axb[m * 256 + tid] = (bf16)(__expf(e[m * 256 + tid] - rmaxS[m]) * rrcpS[m]);
    ayb[m * 256 + tid] = (bf16)(__expf(e[tid * 256 + m] - cm) * crcp);
  }
}

// Fused: v = wv@x + bv (K=1024) -> LDS ; o = v @ attn^T (K=256) ; out = gamma*o + x
// Block: 64 c-rows x 256 m-cols, 4 waves (each 64x64 cols slice).
__global__ __launch_bounds__(256) void k_vapply(
    const bf16* __restrict__ xbT, const bf16* __restrict__ ybT,
    const bf16* __restrict__ wv1b, const bf16* __restrict__ wv2b,
    const float* __restrict__ bv1, const float* __restrict__ bv2,
    const bf16* __restrict__ ax, const bf16* __restrict__ ay,
    const float* __restrict__ xin0, const float* __restrict__ yin0,
    const float* __restrict__ g1, const float* __restrict__ g2,
    float* __restrict__ out) {
  __shared__ __align__(16) char smem[53248];  // As 4KB @0 | Bs 16KB @4096 | vt 32KB @20480
  int ct = blockIdx.x, br = blockIdx.y, b = blockIdx.z;
  const bf16* A1 = (br ? wv2b : wv1b) + (size_t)ct * 64 * C_;
  const bf16* Bt1 = (br ? ybT : xbT) + (size_t)b * N_ * C_;
  const float* bias = br ? bv2 : bv1;
  const bf16* attn = (br ? ay : ax) + (size_t)b * N_ * N_;
  const float* xin = (br ? yin0 : xin0) + (size_t)b * C_ * N_ + (size_t)ct * 64 * N_;
  float gamma = br ? g2[0] : g1[0];
  float* o = out + (size_t)br * B_ * C_ * N_ + (size_t)b * C_ * N_ + (size_t)ct * 64 * N_;
  const int tid = threadIdx.x, l = tid & 63, wid = tid >> 6;
  floatx4 acc[4][4];
  floatx4 z = {0.f, 0.f, 0.f, 0.f};
#pragma unroll
  for (int i = 0; i < 4; ++i)
#pragma unroll
    for (int j = 0; j < 4; ++j) acc[i][j] = z;

  // ---- GEMM1: v[64][256] over K=1024 ----
  for (int kt = 0; kt < 32; ++kt) {
    const int k0 = kt * 32;
    {
      int row = (wid << 4) + (l >> 2);                    // 0..63 (c-local)
      int q = (l & 3) ^ ((row >> 1) & 3);
      async16(A1 + (size_t)row * C_ + k0 + q * 8, smem + (wid << 10));
    }
#pragma unroll
    for (int s = 0; s < 4; ++s) {
      int row = (s << 6) + (wid << 4) + (l >> 2);         // 0..255 (n)
      int q = (l & 3) ^ ((row >> 1) & 3);
      async16(Bt1 + (size_t)row * C_ + k0 + q * 8, smem + 4096 + (s << 12) + (wid << 10));
    }
    __syncthreads();
    bf16x8 af[4], bfr[4];
#pragma unroll
    for (int t = 0; t < 4; ++t) {
      int m = t * 16 + (l & 15);
      af[t] = *(const bf16x8*)(smem + m * 64 + ((((l >> 4) ^ ((m >> 1) & 3)) << 4)));
      int n = (wid << 6) + t * 16 + (l & 15);
      bfr[t] = *(const bf16x8*)(smem + 4096 + n * 64 + ((((l >> 4) ^ ((n >> 1) & 3)) << 4)));
    }
#pragma unroll
    for (int tm = 0; tm < 4; ++tm)
#pragma unroll
      for (int tn = 0; tn < 4; ++tn)
        acc[tm][tn] = __builtin_amdgcn_mfma_f32_16x16x32_bf16(af[tm], bfr[tn], acc[tm][tn], 0, 0, 0);
    __syncthreads();
  }

  // ---- v += bias, cast bf16, swizzled into vt LDS ----
  char* vt = smem + 20480;
#pragma unroll
  for (int tm = 0; tm < 4; ++tm)
#pragma unroll
    for (int r = 0; r < 4; ++r) {
      int rr = tm * 16 + ((l >> 4) << 2) + r;             // c-local 0..63
      float bkv = bias[ct * 64 + rr];
#pragma unroll
      for (int tn = 0; tn < 4; ++tn) {
        int n = (wid << 6) + tn * 16 + (l & 15);
        int ch = (n >> 3) ^ (rr & 7);
        *(bf16*)(vt + rr * 512 + ch * 16 + ((n & 7) << 1)) = (bf16)(acc[tm][tn][r] + bkv);
      }
    }
  __syncthreads();

  // ---- GEMM2: o[64][256] = vt @ attn^T over K=256 ----
#pragma unroll
  for (int i = 0; i < 4; ++i)
#pragma unroll
    for (int j = 0; j < 4; ++j) acc[i][j] = z;
  for (int kt = 0; kt < 8; ++kt) {
    const int k0 = kt * 32;
#pragma unroll
    for (int s = 0; s < 4; ++s) {
      int row = (s << 6) + (wid << 4) + (l >> 2);         // m 0..255
      int q = (l & 3) ^ ((row >> 1) & 3);
      async16(attn + (size_t)row * N_ + k0 + q * 8, smem + 4096 + (s << 12) + (wid << 10));
    }
    __syncthreads();
    bf16x8 af[4], bfr[4];
#pragma unroll
    for (int t = 0; t < 4; ++t) {
      int m = t * 16 + (l & 15);                          // vt row (c-local)
      int ch = ((k0 >> 3) + (l >> 4)) ^ (m & 7);
      af[t] = *(const bf16x8*)(vt + m * 512 + (ch << 4));
      int n = (wid << 6) + t * 16 + (l & 15);
      bfr[t] = *(const bf16x8*)(smem + 4096 + n * 64 + ((((l >> 4) ^ ((n >> 1) & 3)) << 4)));
    }
#pragma unroll
    for (int tm = 0; tm < 4; ++tm)
#pragma unroll
      for (int tn = 0; tn < 4; ++tn)
        acc[tm][tn] = __builtin_amdgcn_mfma_f32_16x16x32_bf16(af[tm], bfr[tn], acc[tm][tn], 0, 0, 0);
    __syncthreads();
  }

  // ---- epilogue: out = gamma*o + x (fp32, exact for gamma=0) ----
#pragma unroll
  for (int tm = 0; tm < 4; ++tm)
#pragma unroll
    for (int tn = 0; tn < 4; ++tn)
#pragma unroll
      for (int r = 0; r < 4; ++r) {
        int rr = tm * 16 + ((l >> 4) << 2) + r;
        int m = (wid << 6) + tn * 16 + (l & 15);
        int idx = rr * N_ + m;
        o[idx] = gamma * acc[tm][tn][r] + xin[idx];
      }
}

// safety fallback if workspace is too small: out_x = x, out_y = y (exact when gamma==0)
__global__ __launch_bounds__(256) void k_fallback(const float4* __restrict__ x,
                                                  const float4* __restrict__ y,
                                                  float4* __restrict__ out) {
  size_t i = (size_t)blockIdx.x * 256 + threadIdx.x;
  out[i] = x[i];
  out[4194304 + i] = y[i];
}

extern "C" void kernel_launch(void* const* d_in, const int* in_sizes, int n_in,
                              void* d_out, int out_size, void* d_ws, size_t ws_size,
                              hipStream_t stream) {
  const float* x   = (const float*)d_in[0];
  const float* y   = (const float*)d_in[1];
  const float* wk1 = (const float*)d_in[2];
  const float* bk1 = (const float*)d_in[3];
  const float* wk2 = (const float*)d_in[4];
  const float* bk2 = (const float*)d_in[5];
  const float* wv1 = (const float*)d_in[6];
  const float* bv1 = (const float*)d_in[7];
  const float* wv2 = (const float*)d_in[8];
  const float* bv2 = (const float*)d_in[9];
  const float* g1  = (const float*)d_in[10];
  const float* g2  = (const float*)d_in[11];
  float* out = (float*)d_out;

  if (ws_size < WS_NEEDED) {
    k_fallback<<<16384, 256, 0, stream>>>((const float4*)x, (const float4*)y, (float4*)out);
    return;
  }

  char* ws = (char*)d_ws;
  bf16* xbT  = (bf16*)(ws + OFF_XBT);
  bf16* ybT  = (bf16*)(ws + OFF_YBT);
  bf16* wk1b = (bf16*)(ws + OFF_WK1);
  bf16* wk2b = (bf16*)(ws + OFF_WK2);
  bf16* wv1b = (bf16*)(ws + OFF_WV1);
  bf16* wv2b = (bf16*)(ws + OFF_WV2);
  bf16* kxT  = (bf16*)(ws + OFF_KXT);
  bf16* kyT  = (bf16*)(ws + OFF_KYT);
  bf16* axp  = (bf16*)(ws + OFF_AX);
  bf16* ayp  = (bf16*)(ws + OFF_AY);
  // E lives in the (dead-until-later) out_y region of d_out
  float* E = out + (size_t)B_ * C_ * N_;

  k_xpose<<<dim3(4, 16, 64), 256, 0, stream>>>(x, xbT);
  k_xpose<<<dim3(4, 16, 64), 256, 0, stream>>>(y, ybT);
  k_cvt<<<128, 256, 0, stream>>>(wk1, wk1b, 32768);
  k_cvt<<<128, 256, 0, stream>>>(wk2, wk2b, 32768);
  k_cvt<<<1024, 256, 0, stream>>>(wv1, wv1b, 262144);
  k_cvt<<<1024, 256, 0, stream>>>(wv2, wv2b, 262144);
  k_projk<<<dim3(2, 2, 64), 256, 0, stream>>>(xbT, ybT, wk1b, wk2b, bk1, bk2, kxT, kyT);
  k_energy<<<dim3(2, 2, 64), 256, 0, stream>>>(kxT, kyT, E);
  k_softmax<<<64, 256, 0, stream>>>(E, axp, ayp);
  k_vapply<<<dim3(16, 2, 64), 256, 0, stream>>>(xbT, ybT, wv1b, wv2b, bv1, bv2,
                                                axp, ayp, x, y, g1, g2, out);
}

// Round 2
// 530.170 us; speedup vs baseline: 1.1954x; 1.1954x over previous
//
#include <hip/hip_runtime.h>
#include <hip/hip_bf16.h>
#include <stdint.h>

// CoAttention: B=64, C=1024, H=W=16 (N=256), CK=128.
#define B_  64
#define C_  1024
#define CK_ 128
#define N_  256

typedef __bf16 bf16;
typedef __attribute__((ext_vector_type(8))) __bf16 bf16x8;
typedef __attribute__((ext_vector_type(4))) __bf16 bf16x4;
typedef __attribute__((ext_vector_type(4))) float floatx4;

// ---- workspace layout (bytes) ----
constexpr size_t OFF_XBT = 0;                 // bf16 [64][256][1024]
constexpr size_t OFF_YBT = 33554432;
constexpr size_t OFF_WK1 = 67108864;          // bf16 [128][1024]
constexpr size_t OFF_WK2 = 67371008;
constexpr size_t OFF_WV1 = 67633152;          // bf16 [1024][1024]
constexpr size_t OFF_WV2 = 69730304;
constexpr size_t OFF_KXT = 71827456;          // bf16 [64][256][128]
constexpr size_t OFF_KYT = 76021760;
constexpr size_t OFF_AX  = 71827456;          // bf16 [64][256][256] aliases kxT/kyT
constexpr size_t OFF_AY  = 80216064;
constexpr size_t WS_NEEDED = 88604672;

__device__ __forceinline__ void async16(const void* g, void* l) {
  __builtin_amdgcn_global_load_lds((const __attribute__((address_space(1))) void*)g,
                                   (__attribute__((address_space(3))) void*)l, 16, 0, 0);
}

// fp32 [C][N] -> bf16 [N][C] transpose; z<64: x-tensor, else y-tensor
__global__ __launch_bounds__(256) void k_xpose(const float* __restrict__ xin,
                                               const float* __restrict__ yin,
                                               bf16* __restrict__ xo, bf16* __restrict__ yo) {
  __shared__ float tile[64][65];
  int nt = blockIdx.x, ct = blockIdx.y, z = blockIdx.z;
  int b = z & 63;
  const float* in = (z < 64) ? xin : yin;
  bf16* out = (z < 64) ? xo : yo;
  const float* src = in + (size_t)b * C_ * N_ + (size_t)ct * 64 * N_ + nt * 64;
  bf16* dst = out + (size_t)b * N_ * C_ + (size_t)nt * 64 * C_ + ct * 64;
  int c4 = (threadIdx.x & 15) * 4, r0 = threadIdx.x >> 4;
#pragma unroll
  for (int i = 0; i < 4; ++i) {
    int r = r0 + i * 16;                       // c-local row
    float4 v = *(const float4*)(src + r * N_ + c4);
    tile[r][c4 + 0] = v.x; tile[r][c4 + 1] = v.y;
    tile[r][c4 + 2] = v.z; tile[r][c4 + 3] = v.w;
  }
  __syncthreads();
#pragma unroll
  for (int i = 0; i < 4; ++i) {
    int r = r0 + i * 16;                       // n-local row
    bf16x4 o;
    o[0] = (bf16)tile[c4 + 0][r]; o[1] = (bf16)tile[c4 + 1][r];
    o[2] = (bf16)tile[c4 + 2][r]; o[3] = (bf16)tile[c4 + 3][r];
    *(bf16x4*)(dst + (size_t)r * C_ + c4) = o;
  }
}

// two fp32->bf16 conversions in one launch
__global__ __launch_bounds__(256) void k_cvt2(const float* __restrict__ inA,
                                              const float* __restrict__ inB,
                                              bf16* __restrict__ outA, bf16* __restrict__ outB,
                                              int n4each) {
  int i = blockIdx.x * 256 + threadIdx.x;
  const float* in = (i < n4each) ? inA : inB;
  bf16* out = (i < n4each) ? outA : outB;
  int j = (i < n4each) ? i : (i - n4each);
  if (i < 2 * n4each) {
    float4 v = ((const float4*)in)[j];
    bf16x4 o;
    o[0] = (bf16)v.x; o[1] = (bf16)v.y; o[2] = (bf16)v.z; o[3] = (bf16)v.w;
    ((bf16x4*)out)[j] = o;
  }
}

// 128x128 GEMM core, double-buffered LDS, one barrier/iter.
// LDS: As0@0, As1@8192 (8KB each), Bs0@16384, Bs1@24576. smem must be 32KB.
template <int KITERS>
__device__ __forceinline__ void gemm128_core(const bf16* __restrict__ Ag, int ldA,
                                             const bf16* __restrict__ Bg, int ldB,
                                             char* smem, floatx4 (&acc)[4][4]) {
  const int tid = threadIdx.x;
  const int l = tid & 63, wid = tid >> 6;
  const int wm = wid & 1, wn = wid >> 1;
  auto issue = [&](int kt, int buf) {
    const int k0 = kt * 32;
#pragma unroll
    for (int s = 0; s < 2; ++s) {
      int row = (s << 6) + (wid << 4) + (l >> 2);
      int q = (l & 3) ^ ((row >> 1) & 3);
      async16(Ag + (size_t)row * ldA + k0 + q * 8, smem + (buf << 13) + (s << 12) + (wid << 10));
      async16(Bg + (size_t)row * ldB + k0 + q * 8, smem + 16384 + (buf << 13) + (s << 12) + (wid << 10));
    }
  };
  auto compute = [&](int buf) {
    const char* As = smem + (buf << 13);
    const char* Bs = smem + 16384 + (buf << 13);
    bf16x8 af[4], bfr[4];
#pragma unroll
    for (int t = 0; t < 4; ++t) {
      int m = (wm << 6) + t * 16 + (l & 15);
      af[t] = *(const bf16x8*)(As + m * 64 + (((l >> 4) ^ ((m >> 1) & 3)) << 4));
      int n = (wn << 6) + t * 16 + (l & 15);
      bfr[t] = *(const bf16x8*)(Bs + n * 64 + (((l >> 4) ^ ((n >> 1) & 3)) << 4));
    }
#pragma unroll
    for (int tm = 0; tm < 4; ++tm)
#pragma unroll
      for (int tn = 0; tn < 4; ++tn)
        acc[tm][tn] = __builtin_amdgcn_mfma_f32_16x16x32_bf16(af[tm], bfr[tn], acc[tm][tn], 0, 0, 0);
  };
  issue(0, 0);
  for (int kt = 0; kt < KITERS; kt += 2) {
    __syncthreads();
    issue(kt + 1, 1);
    compute(0);
    __syncthreads();
    if (kt + 2 < KITERS) issue(kt + 2, 0);
    compute(1);
  }
}

// kT[n][o] = sum_c xbT[n][c]*wk[o][c] + bk[o]
__global__ __launch_bounds__(256) void k_projk(
    const bf16* __restrict__ xbT, const bf16* __restrict__ ybT,
    const bf16* __restrict__ wk1b, const bf16* __restrict__ wk2b,
    const float* __restrict__ bk1, const float* __restrict__ bk2,
    bf16* __restrict__ kxT, bf16* __restrict__ kyT) {
  __shared__ __align__(16) char smem[32768];
  int mt = blockIdx.x, br = blockIdx.y, b = blockIdx.z;
  const bf16* A = (br ? ybT : xbT) + (size_t)b * N_ * C_ + (size_t)mt * 128 * C_;
  const bf16* Bt = br ? wk2b : wk1b;
  const float* bias = br ? bk2 : bk1;
  bf16* out = (br ? kyT : kxT) + (size_t)b * N_ * CK_ + (size_t)mt * 128 * CK_;
  floatx4 acc[4][4];
  floatx4 z = {0.f, 0.f, 0.f, 0.f};
#pragma unroll
  for (int i = 0; i < 4; ++i)
#pragma unroll
    for (int j = 0; j < 4; ++j) acc[i][j] = z;
  gemm128_core<32>(A, C_, Bt, C_, smem, acc);
  const int l = threadIdx.x & 63, wid = threadIdx.x >> 6;
  const int wm = wid & 1, wn = wid >> 1;
#pragma unroll
  for (int tn = 0; tn < 4; ++tn) {
    int oc = (wn << 6) + tn * 16 + (l & 15);
    float bkv = bias[oc];
#pragma unroll
    for (int tm = 0; tm < 4; ++tm)
#pragma unroll
      for (int r = 0; r < 4; ++r) {
        int row = (wm << 6) + tm * 16 + ((l >> 4) << 2) + r;
        out[row * CK_ + oc] = (bf16)(acc[tm][tn][r] + bkv);
      }
  }
}

// E[m][n] = sum_o kxT[m][o]*kyT[n][o]
__global__ __launch_bounds__(256) void k_energy(const bf16* __restrict__ kxT,
                                                const bf16* __restrict__ kyT,
                                                float* __restrict__ E) {
  __shared__ __align__(16) char smem[32768];
  int mt = blockIdx.x, nt = blockIdx.y, b = blockIdx.z;
  const bf16* A = kxT + (size_t)b * N_ * CK_ + (size_t)mt * 128 * CK_;
  const bf16* Bt = kyT + (size_t)b * N_ * CK_ + (size_t)nt * 128 * CK_;
  float* out = E + (size_t)b * N_ * N_ + (size_t)mt * 128 * N_ + nt * 128;
  floatx4 acc[4][4];
  floatx4 z = {0.f, 0.f, 0.f, 0.f};
#pragma unroll
  for (int i = 0; i < 4; ++i)
#pragma unroll
    for (int j = 0; j < 4; ++j) acc[i][j] = z;
  gemm128_core<4>(A, CK_, Bt, CK_, smem, acc);
  const int l = threadIdx.x & 63, wid = threadIdx.x >> 6;
  const int wm = wid & 1, wn = wid >> 1;
#pragma unroll
  for (int tm = 0; tm < 4; ++tm)
#pragma unroll
    for (int tn = 0; tn < 4; ++tn)
#pragma unroll
      for (int r = 0; r < 4; ++r) {
        int row = (wm << 6) + tm * 16 + ((l >> 4) << 2) + r;
        int col = (wn << 6) + tn * 16 + (l & 15);
        out[row * N_ + col] = acc[tm][tn][r];
      }
}

// ax[m][n] = softmax_n E[m][n]; ay[i][j] = softmax over first index: exp(E[j][i]-cmax_i)*crcp_i
// grid (64 b, 4 q): block handles rows/cols q*64..q*64+64
__global__ __launch_bounds__(256) void k_softmax(const float* __restrict__ E,
                                                 bf16* __restrict__ ax,
                                                 bf16* __restrict__ ay) {
  __shared__ float slabT[64][257];   // [col-local][row]
  __shared__ float red[16][64];
  __shared__ float cmaxS[64], crcpS[64], rmaxS[64], rrcpS[64];
  const int b = blockIdx.x, q = blockIdx.y;
  const float* e = E + (size_t)b * N_ * N_;
  const int tid = threadIdx.x, l = tid & 63, wid = tid >> 6;
  const int cg = tid & 15;          // 4-col group
  const int rg = tid >> 4;          // 16 row groups
  // phase 1: load slab E[:, q*64..+64], transpose into slabT, partial col max
  float m4[4] = {-1e30f, -1e30f, -1e30f, -1e30f};
#pragma unroll 4
  for (int k = 0; k < 16; ++k) {
    int r = rg + (k << 4);
    float4 v = *(const float4*)(e + (size_t)r * N_ + q * 64 + cg * 4);
    slabT[cg * 4 + 0][r] = v.x; slabT[cg * 4 + 1][r] = v.y;
    slabT[cg * 4 + 2][r] = v.z; slabT[cg * 4 + 3][r] = v.w;
    m4[0] = fmaxf(m4[0], v.x); m4[1] = fmaxf(m4[1], v.y);
    m4[2] = fmaxf(m4[2], v.z); m4[3] = fmaxf(m4[3], v.w);
  }
#pragma unroll
  for (int j = 0; j < 4; ++j) red[rg][cg * 4 + j] = m4[j];
  __syncthreads();
  if (tid < 64) {
    float mm = red[0][tid];
#pragma unroll
    for (int i = 1; i < 16; ++i) mm = fmaxf(mm, red[i][tid]);
    cmaxS[tid] = mm;
  }
  __syncthreads();
  // phase 2: col sum of exp (from slabT)
  float s4[4] = {0.f, 0.f, 0.f, 0.f};
#pragma unroll 4
  for (int k = 0; k < 16; ++k) {
    int r = rg + (k << 4);
#pragma unroll
    for (int j = 0; j < 4; ++j) s4[j] += __expf(slabT[cg * 4 + j][r] - cmaxS[cg * 4 + j]);
  }
  __syncthreads();
#pragma unroll
  for (int j = 0; j < 4; ++j) red[rg][cg * 4 + j] = s4[j];
  __syncthreads();
  if (tid < 64) {
    float ss = 0.f;
#pragma unroll
    for (int i = 0; i < 16; ++i) ss += red[i][tid];
    crcpS[tid] = 1.0f / ss;
  }
  // phase 3: row stats for rows q*64..+64 (wave per row, shuffle reduce)
  for (int m = wid; m < 64; m += 4) {
    const float* row = e + (size_t)(q * 64 + m) * N_;
    float v0 = row[l], v1 = row[l + 64], v2 = row[l + 128], v3 = row[l + 192];
    float mx = fmaxf(fmaxf(v0, v1), fmaxf(v2, v3));
#pragma unroll
    for (int off = 32; off > 0; off >>= 1) mx = fmaxf(mx, __shfl_xor(mx, off));
    float s = __expf(v0 - mx) + __expf(v1 - mx) + __expf(v2 - mx) + __expf(v3 - mx);
#pragma unroll
    for (int off = 32; off > 0; off >>= 1) s += __shfl_xor(s, off);
    if (l == 0) { rmaxS[m] = mx; rrcpS[m] = 1.0f / s; }
  }
  __syncthreads();
  // phase 4: ax rows (float4 read, bf16x4 store)
  bf16* axb = ax + (size_t)b * N_ * N_;
#pragma unroll 4
  for (int t = 0; t < 16; ++t) {
    int rr = wid * 16 + t;
    float rm = rmaxS[rr], rc = rrcpS[rr];
    float4 v = *(const float4*)(e + (size_t)(q * 64 + rr) * N_ + l * 4);
    bf16x4 o;
    o[0] = (bf16)(__expf(v.x - rm) * rc); o[1] = (bf16)(__expf(v.y - rm) * rc);
    o[2] = (bf16)(__expf(v.z - rm) * rc); o[3] = (bf16)(__expf(v.w - rm) * rc);
    *(bf16x4*)(axb + (size_t)(q * 64 + rr) * N_ + l * 4) = o;
  }
  // phase 5: ay rows i=q*64+rr from slabT column-stats (conflict-free: lane l -> col l+64k)
  bf16* ayb = ay + (size_t)b * N_ * N_;
#pragma unroll 4
  for (int t = 0; t < 16; ++t) {
    int rr = wid * 16 + t;
    float cm = cmaxS[rr], cc = crcpS[rr];
#pragma unroll
    for (int k = 0; k < 4; ++k) {
      int j = l + 64 * k;
      ayb[(size_t)(q * 64 + rr) * N_ + j] = (bf16)(__expf(slabT[rr][j] - cm) * cc);
    }
  }
}

// Fused V: v = wv@x + bv (K=1024, B-stream LDS-dbuf, A direct-to-VGPR prefetch),
// o = v @ attn^T (K=256, B direct-to-VGPR prefetch, no barriers), out = gamma*o + x.
// LDS 32KB: GEMM1 Bs0@0/Bs1@16384; GEMM2 vt@0 (overlays, after barrier).
__global__ __launch_bounds__(256) void k_vapply(
    const bf16* __restrict__ xbT, const bf16* __restrict__ ybT,
    const bf16* __restrict__ wv1b, const bf16* __restrict__ wv2b,
    const float* __restrict__ bv1, const float* __restrict__ bv2,
    const bf16* __restrict__ ax, const bf16* __restrict__ ay,
    const float* __restrict__ xin0, const float* __restrict__ yin0,
    const float* __restrict__ g1, const float* __restrict__ g2,
    float* __restrict__ out) {
  __shared__ __align__(16) char smem[32768];
  // XCD-swizzled decode: all 32 blocks of a given b land on one XCD (id%8 heuristic)
  int id = blockIdx.x;
  int xcd = id & 7;
  int idx = id >> 3;                 // 0..255
  int b = xcd + ((idx >> 5) << 3);   // 0..63
  int inner = idx & 31;
  int ct = inner & 15, br = inner >> 4;

  const bf16* A1 = (br ? wv2b : wv1b) + (size_t)ct * 64 * C_;
  const bf16* Bt1 = (br ? ybT : xbT) + (size_t)b * N_ * C_;
  const float* bias = br ? bv2 : bv1;
  const bf16* attn = (br ? ay : ax) + (size_t)b * N_ * N_;
  const float* xin = (br ? yin0 : xin0) + (size_t)b * C_ * N_ + (size_t)ct * 64 * N_;
  float gamma = br ? g2[0] : g1[0];
  float* o = out + (size_t)br * B_ * C_ * N_ + (size_t)b * C_ * N_ + (size_t)ct * 64 * N_;
  const int tid = threadIdx.x, l = tid & 63, wid = tid >> 6;

  auto loadA = [&](int kt, bf16x8 (&af)[4]) {
    const bf16* p = A1 + (size_t)(l & 15) * C_ + kt * 32 + ((l >> 4) << 3);
#pragma unroll
    for (int t = 0; t < 4; ++t) af[t] = *(const bf16x8*)(p + (size_t)t * 16 * C_);
  };
  auto issueB = [&](int kt, int buf) {
    const int k0 = kt * 32;
#pragma unroll
    for (int s = 0; s < 4; ++s) {
      int row = (s << 6) + (wid << 4) + (l >> 2);
      int q = (l & 3) ^ ((row >> 1) & 3);
      async16(Bt1 + (size_t)row * C_ + k0 + q * 8, smem + (buf << 14) + (s << 12) + (wid << 10));
    }
  };
  floatx4 acc[4][4];
  floatx4 z = {0.f, 0.f, 0.f, 0.f};
#pragma unroll
  for (int i = 0; i < 4; ++i)
#pragma unroll
    for (int j = 0; j < 4; ++j) acc[i][j] = z;

  auto compute1 = [&](int buf, bf16x8 (&af)[4]) {
    const char* Bs = smem + (buf << 14);
    bf16x8 bfr[4];
#pragma unroll
    for (int t = 0; t < 4; ++t) {
      int n = (wid << 6) + t * 16 + (l & 15);
      bfr[t] = *(const bf16x8*)(Bs + n * 64 + (((l >> 4) ^ ((n >> 1) & 3)) << 4));
    }
#pragma unroll
    for (int tm = 0; tm < 4; ++tm)
#pragma unroll
      for (int tn = 0; tn < 4; ++tn)
        acc[tm][tn] = __builtin_amdgcn_mfma_f32_16x16x32_bf16(af[tm], bfr[tn], acc[tm][tn], 0, 0, 0);
  };

  // ---- GEMM1: v[64][256] over K=1024, dbuf + reg-prefetch, 1 barrier/iter ----
  bf16x8 afA[4], afB[4];
  issueB(0, 0);
  loadA(0, afA);
  for (int kt = 0; kt < 32; kt += 2) {
    __syncthreads();
    issueB(kt + 1, 1);
    loadA(kt + 1, afB);
    compute1(0, afA);
    __syncthreads();
    if (kt + 2 < 32) { issueB(kt + 2, 0); loadA(kt + 2, afA); }
    compute1(1, afB);
  }
  __syncthreads();   // all Bs reads done; smem region becomes vt

  // ---- v += bias, cast bf16, swizzled into vt ----
  char* vt = smem;
#pragma unroll
  for (int tm = 0; tm < 4; ++tm)
#pragma unroll
    for (int r = 0; r < 4; ++r) {
      int rr = tm * 16 + ((l >> 4) << 2) + r;             // c-local 0..63
      float bkv = bias[ct * 64 + rr];
#pragma unroll
      for (int tn = 0; tn < 4; ++tn) {
        int n = (wid << 6) + tn * 16 + (l & 15);
        int ch = (n >> 3) ^ (rr & 7);
        *(bf16*)(vt + rr * 512 + ch * 16 + ((n & 7) << 1)) = (bf16)(acc[tm][tn][r] + bkv);
      }
    }

  auto loadB2 = [&](int kt, bf16x8 (&bb)[4]) {
    const bf16* p = attn + (size_t)((wid << 6) + (l & 15)) * N_ + kt * 32 + ((l >> 4) << 3);
#pragma unroll
    for (int t = 0; t < 4; ++t) bb[t] = *(const bf16x8*)(p + (size_t)t * 16 * N_);
  };
  auto compute2 = [&](int kt, bf16x8 (&bb)[4]) {
    bf16x8 af[4];
#pragma unroll
    for (int t = 0; t < 4; ++t) {
      int m = t * 16 + (l & 15);
      int ch = ((kt << 2) + (l >> 4)) ^ (m & 7);
      af[t] = *(const bf16x8*)(vt + m * 512 + (ch << 4));
    }
#pragma unroll
    for (int tm = 0; tm < 4; ++tm)
#pragma unroll
      for (int tn = 0; tn < 4; ++tn)
        acc[tm][tn] = __builtin_amdgcn_mfma_f32_16x16x32_bf16(af[tm], bb[tn], acc[tm][tn], 0, 0, 0);
  };

  // ---- GEMM2: o[64][256] = vt @ attn^T over K=256, reg-prefetch, no barriers ----
  bf16x8 bfA[4], bfB[4];
  loadB2(0, bfA);          // issued before barrier; drained by it
  __syncthreads();         // vt visible
#pragma unroll
  for (int i = 0; i < 4; ++i)
#pragma unroll
    for (int j = 0; j < 4; ++j) acc[i][j] = z;
  for (int kt = 0; kt < 8; kt += 2) {
    loadB2(kt + 1, bfB);
    compute2(kt, bfA);
    if (kt + 2 < 8) loadB2(kt + 2, bfA);
    compute2(kt + 1, bfB);
  }

  // ---- epilogue: out = gamma*o + x ----
#pragma unroll
  for (int tm = 0; tm < 4; ++tm)
#pragma unroll
    for (int tn = 0; tn < 4; ++tn)
#pragma unroll
      for (int r = 0; r < 4; ++r) {
        int rr = tm * 16 + ((l >> 4) << 2) + r;
        int m = (wid << 6) + tn * 16 + (l & 15);
        int idx2 = rr * N_ + m;
        o[idx2] = gamma * acc[tm][tn][r] + xin[idx2];
      }
}

__global__ __launch_bounds__(256) void k_fallback(const float4* __restrict__ x,
                                                  const float4* __restrict__ y,
                                                  float4* __restrict__ out) {
  size_t i = (size_t)blockIdx.x * 256 + threadIdx.x;
  out[i] = x[i];
  out[4194304 + i] = y[i];
}

extern "C" void kernel_launch(void* const* d_in, const int* in_sizes, int n_in,
                              void* d_out, int out_size, void* d_ws, size_t ws_size,
                              hipStream_t stream) {
  const float* x   = (const float*)d_in[0];
  const float* y   = (const float*)d_in[1];
  const float* wk1 = (const float*)d_in[2];
  const float* bk1 = (const float*)d_in[3];
  const float* wk2 = (const float*)d_in[4];
  const float* bk2 = (const float*)d_in[5];
  const float* wv1 = (const float*)d_in[6];
  const float* bv1 = (const float*)d_in[7];
  const float* wv2 = (const float*)d_in[8];
  const float* bv2 = (const float*)d_in[9];
  const float* g1  = (const float*)d_in[10];
  const float* g2  = (const float*)d_in[11];
  float* out = (float*)d_out;

  if (ws_size < WS_NEEDED) {
    k_fallback<<<16384, 256, 0, stream>>>((const float4*)x, (const float4*)y, (float4*)out);
    return;
  }

  char* ws = (char*)d_ws;
  bf16* xbT  = (bf16*)(ws + OFF_XBT);
  bf16* ybT  = (bf16*)(ws + OFF_YBT);
  bf16* wk1b = (bf16*)(ws + OFF_WK1);
  bf16* wk2b = (bf16*)(ws + OFF_WK2);
  bf16* wv1b = (bf16*)(ws + OFF_WV1);
  bf16* wv2b = (bf16*)(ws + OFF_WV2);
  bf16* kxT  = (bf16*)(ws + OFF_KXT);
  bf16* kyT  = (bf16*)(ws + OFF_KYT);
  bf16* axp  = (bf16*)(ws + OFF_AX);
  bf16* ayp  = (bf16*)(ws + OFF_AY);
  float* E = out + (size_t)B_ * C_ * N_;   // dead out_y region

  k_xpose<<<dim3(4, 16, 128), 256, 0, stream>>>(x, y, xbT, ybT);
  k_cvt2<<<256, 256, 0, stream>>>(wk1, wk2, wk1b, wk2b, 32768);
  k_cvt2<<<2048, 256, 0, stream>>>(wv1, wv2, wv1b, wv2b, 262144);
  k_projk<<<dim3(2, 2, 64), 256, 0, stream>>>(xbT, ybT, wk1b, wk2b, bk1, bk2, kxT, kyT);
  k_energy<<<dim3(2, 2, 64), 256, 0, stream>>>(kxT, kyT, E);
  k_softmax<<<dim3(64, 4), 256, 0, stream>>>(E, axp, ayp);
  k_vapply<<<2048, 256, 0, stream>>>(xbT, ybT, wv1b, wv2b, bv1, bv2,
                                     axp, ayp, x, y, g1, g2, out);
}